// Round 5
// baseline (821.978 us; speedup 1.0000x reference)
//
#include <hip/hip_runtime.h>
#include <hip/hip_bf16.h>
#include <type_traits>

typedef __hip_bfloat16 bf16;
typedef __attribute__((ext_vector_type(8))) short s8v;   // 8 x bf16 (16B)
typedef __attribute__((ext_vector_type(4))) short s4v;   // 4 x bf16 (8B)
typedef __attribute__((ext_vector_type(4))) float f4v;   // MFMA C/D frag

#define MFMA16(A, B, C) __builtin_amdgcn_mfma_f32_16x16x32_bf16((A), (B), (C), 0, 0, 0)

constexpr int SEQ = 2048;
constexpr int DIM = 4096;
constexpr int NH  = 32;
constexpr int HD  = 128;

__device__ __forceinline__ short f2bs(float f) {
    __hip_bfloat16_raw r = __float2bfloat16(f);
    return (short)r.x;
}

// async global->LDS, 16B per lane. HW semantics: wave-uniform LDS base +
// lane*16; lane i's global data lands at base + i*16.
__device__ __forceinline__ void ld_g2l(const bf16* g, bf16* l) {
    __builtin_amdgcn_global_load_lds(
        (const __attribute__((address_space(1))) void*)g,
        (__attribute__((address_space(3))) void*)l, 16, 0, 0);
}

// ---------------------------------------------------------------------------
// fp32 -> bf16 elementwise convert (float4 loads)
// ---------------------------------------------------------------------------
__global__ void convert_bf16(const float* __restrict__ s, bf16* __restrict__ d) {
    int i = blockIdx.x * blockDim.x + threadIdx.x;
    float4 f = ((const float4*)s)[i];
    s4v o;
    o[0] = f2bs(f.x); o[1] = f2bs(f.y); o[2] = f2bs(f.z); o[3] = f2bs(f.w);
    *(s4v*)(d + (size_t)i * 4) = o;
}

// ---------------------------------------------------------------------------
// fp32 [R][C] -> bf16 [C][R] transpose + convert, vectorized both sides.
// ---------------------------------------------------------------------------
__global__ __launch_bounds__(256) void convt_bf16(const float* __restrict__ src,
                                                  bf16* __restrict__ dst,
                                                  int R, int C) {
    __shared__ float t[64][65];
    const int c0 = blockIdx.x * 64, r0 = blockIdx.y * 64;
    const int tid = threadIdx.x;
    const int lr = tid >> 4;             // 0..15
    const int lc = (tid & 15) * 4;       // 0..60
#pragma unroll
    for (int i = 0; i < 4; i++) {
        float4 f = *(const float4*)(src + (size_t)(r0 + lr + 16 * i) * C + c0 + lc);
        t[lr + 16 * i][lc]     = f.x;
        t[lr + 16 * i][lc + 1] = f.y;
        t[lr + 16 * i][lc + 2] = f.z;
        t[lr + 16 * i][lc + 3] = f.w;
    }
    __syncthreads();
    const int oc = tid >> 2;             // output row (source col) 0..63
#pragma unroll
    for (int i = 0; i < 2; i++) {
        int rr = (tid & 3) * 8 + 32 * i; // 0..56 step 8
        s8v o;
#pragma unroll
        for (int e = 0; e < 8; e++) o[e] = f2bs(t[rr + e][oc]);
        *(s8v*)(dst + (size_t)(c0 + oc) * R + r0 + rr) = o;
    }
}

// ---------------------------------------------------------------------------
// 256x256 8-phase GEMM (m201 geometry, R2-proven schedule & swizzle):
//   C = A[M,K] * Bt[N,K]^T, bf16 in, CT out. BK=64, 512 thr = 8 waves
//   (2M x 4N), per-wave 128x64 -> 64 MFMA/K-tile/wave, 8 MFMA/barrier.
//   LDS 128KB: As[2][256][64] + Bs[2][256][64], double-buffered.
//
// QKV-fusion support: output column ct selects buffer (ct>>12)*cstride,
//   inner col ct&4095, ldc=DIM. 256 | 4096 so blocks never straddle.
//
// XCD remap (requires nwg%8==0): lin%8 = XCD; nv=(lin&7)*(nwg/8)+lin/8;
//   bm=nv/NBN, bn=nv%NBN -> each XCD owns whole bm-rows: co-resident blocks
//   share a 2MB A-panel (L2-fits); B panels stream via LLC.
//
// Swizzle (verified R2/R4): 16B-group g=(byte>>4)&7; slot g holds global
//   group g^(row&7); global_load_lds keeps LINEAR LDS dest, permutation
//   applied to per-lane GLOBAL source (rule #21); reads XOR the same term
//   -> 2 lanes/bank (free). row&7 == m16&7 for all fragment rows.
//
// Schedule per K-tile t (buf cur=t&1; stage t+2 -> SAME buf cur):
//   ph1: ds_read A(m0-3)x2 + B(n0-1)x2 (12) | MFMA (m0-3)x(n0-1)
//   ph2: ds_read B(n2-3)x2 (4)             | MFMA (m0-3)x(n2-3)
//   ph3: ds_read A(m4-7)x2 (8) | stage B(t+2) 4 loads | MFMA (m4-7)x(n0-1)
//   ph4: stage A(t+2) 4 loads; vmcnt(8)    | MFMA (m4-7)x(n2-3)
//   each phase: [reads][stage][s_barrier][lgkm0+schedbar][setprio1 MFMA][bar]
// Hazard proof (as R2): B of cur last read ph2 -> staged ph3 (ph2's closing
//   barrier orders all waves' lgkm0-complete reads before any ph3 stage);
//   A last read ph3 -> staged ph4. vmcnt(8) at ph4 = exactly t+2's 8 loads
//   outstanding -> t+1's 8 (issued prev iter) retired in order -> next
//   iter's reads safe after the closing barrier.
// ---------------------------------------------------------------------------
template <typename CT>
__global__ __launch_bounds__(512, 2) void gemm_256(const bf16* __restrict__ A,
                                                   const bf16* __restrict__ Bt,
                                                   CT* __restrict__ C,
                                                   int K, size_t cstride) {
    __shared__ bf16 As_[2][256 * 64];
    __shared__ bf16 Bs_[2][256 * 64];
    const int tid  = threadIdx.x;
    const int lane = tid & 63;
    const int wv   = tid >> 6;
    const int m16  = lane & 15;
    const int quad = lane >> 4;
    const int wm   = wv >> 2, wn = wv & 3;   // 2M x 4N wave grid

    const int NBN = (int)gridDim.x;
    const int lin = (int)(blockIdx.y * gridDim.x + blockIdx.x);
    const int nw8 = (int)(gridDim.x * gridDim.y) >> 3;
    const int nv  = (lin & 7) * nw8 + (lin >> 3);
    const int bm  = nv / NBN;
    const int bn  = nv - bm * NBN;

    const bf16* Ab = A  + (size_t)bm * 256 * K;
    const bf16* Bb = Bt + (size_t)bn * 256 * K;

    // staging geometry: STAGEH = one 128-row x 64-col half-tile (2 loads)
    const int row0 = tid >> 3;                       // 0..63
    const int gc8  = ((tid & 7) ^ (row0 & 7)) * 8;   // inverse-swizzled src
    const int dst0 = wv * 512;                       // elems; +lane*8 by HW
    const int dst1 = 4096 + wv * 512;

    // read geometry
    const int aB  = (wm * 128 + m16) * 64;
    const int bB  = (wn * 64 + m16) * 64;
    const int swz = m16 & 7;
    const int c0k = ((0 + quad) ^ swz) * 8;   // ks=0 col offset (bf16 units)
    const int c1k = ((4 + quad) ^ swz) * 8;   // ks=1

    const int NT = K >> 6;

    f4v acc[8][4] = {};
    s8v aR[4][2], bR[4][2];

#define STAGEH(gb, lb) do { \
        ld_g2l((gb) + (size_t)row0 * K + gc8, (lb) + dst0); \
        ld_g2l((gb) + (size_t)(row0 + 64) * K + gc8, (lb) + dst1); } while (0)
#define LDA_(i, ks)  aR[i][ks] = *(const s8v*)(Ac + aB + (i) * 1024 + ((ks) ? c1k : c0k))
#define LDAU_(i, ks) aR[i][ks] = *(const s8v*)(Ac + aB + (i) * 1024 + 4096 + ((ks) ? c1k : c0k))
#define LDB_(j, ks)  bR[j][ks] = *(const s8v*)(Bc + bB + (j) * 1024 + ((ks) ? c1k : c0k))
#define MMQ(ai, i, j) do { acc[ai][j] = MFMA16(aR[i][0], bR[j][0], acc[ai][j]); \
                           acc[ai][j] = MFMA16(aR[i][1], bR[j][1], acc[ai][j]); } while (0)
#define BARX()  __builtin_amdgcn_s_barrier()
#define LGKM0() do { asm volatile("s_waitcnt lgkmcnt(0)" ::: "memory"); \
                     __builtin_amdgcn_sched_barrier(0); } while (0)

    // ---- prologue: stage t0 (8 loads) + t1 (8 loads); wait t0 landed ----
    STAGEH(Ab, As_[0]); STAGEH(Ab + (size_t)128 * K, As_[0] + 8192);
    STAGEH(Bb, Bs_[0]); STAGEH(Bb + (size_t)128 * K, Bs_[0] + 8192);
    STAGEH(Ab + 64, As_[1]); STAGEH(Ab + (size_t)128 * K + 64, As_[1] + 8192);
    STAGEH(Bb + 64, Bs_[1]); STAGEH(Bb + (size_t)128 * K + 64, Bs_[1] + 8192);
    asm volatile("s_waitcnt vmcnt(8)" ::: "memory");
    __builtin_amdgcn_sched_barrier(0);
    BARX();

    for (int t = 0; t < NT; ++t) {
        const int cur = t & 1;
        const bf16* Ac = As_[cur];
        const bf16* Bc = Bs_[cur];
        const bool more = (t + 2 < NT);
        const int k2 = (t + 2) << 6;

        // ---------------- phase 1: (m0-3) x (n0-1) ----------------
        LDA_(0, 0); LDA_(0, 1); LDA_(1, 0); LDA_(1, 1);
        LDA_(2, 0); LDA_(2, 1); LDA_(3, 0); LDA_(3, 1);
        LDB_(0, 0); LDB_(0, 1); LDB_(1, 0); LDB_(1, 1);
        BARX(); LGKM0();
        __builtin_amdgcn_s_setprio(1);
        MMQ(0, 0, 0); MMQ(0, 0, 1); MMQ(1, 1, 0); MMQ(1, 1, 1);
        MMQ(2, 2, 0); MMQ(2, 2, 1); MMQ(3, 3, 0); MMQ(3, 3, 1);
        __builtin_amdgcn_s_setprio(0);
        BARX();

        // ---------------- phase 2: (m0-3) x (n2-3) ----------------
        LDB_(2, 0); LDB_(2, 1); LDB_(3, 0); LDB_(3, 1);
        BARX(); LGKM0();
        __builtin_amdgcn_s_setprio(1);
        MMQ(0, 0, 2); MMQ(0, 0, 3); MMQ(1, 1, 2); MMQ(1, 1, 3);
        MMQ(2, 2, 2); MMQ(2, 2, 3); MMQ(3, 3, 2); MMQ(3, 3, 3);
        __builtin_amdgcn_s_setprio(0);
        BARX();

        // ---------------- phase 3: (m4-7) x (n0-1) | stage B(t+2) --------
        LDAU_(0, 0); LDAU_(0, 1); LDAU_(1, 0); LDAU_(1, 1);
        LDAU_(2, 0); LDAU_(2, 1); LDAU_(3, 0); LDAU_(3, 1);
        if (more) {
            STAGEH(Bb + k2, Bs_[cur]);
            STAGEH(Bb + (size_t)128 * K + k2, Bs_[cur] + 8192);
        }
        BARX(); LGKM0();
        __builtin_amdgcn_s_setprio(1);
        MMQ(4, 0, 0); MMQ(4, 0, 1); MMQ(5, 1, 0); MMQ(5, 1, 1);
        MMQ(6, 2, 0); MMQ(6, 2, 1); MMQ(7, 3, 0); MMQ(7, 3, 1);
        __builtin_amdgcn_s_setprio(0);
        BARX();

        // ---------------- phase 4: (m4-7) x (n2-3) | stage A(t+2) --------
        if (more) {
            STAGEH(Ab + k2, As_[cur]);
            STAGEH(Ab + (size_t)128 * K + k2, As_[cur] + 8192);
            asm volatile("s_waitcnt vmcnt(8)" ::: "memory");
        } else {
            asm volatile("s_waitcnt vmcnt(0)" ::: "memory");
        }
        __builtin_amdgcn_sched_barrier(0);
        BARX();
        __builtin_amdgcn_s_setprio(1);
        MMQ(4, 0, 2); MMQ(4, 0, 3); MMQ(5, 1, 2); MMQ(5, 1, 3);
        MMQ(6, 2, 2); MMQ(6, 2, 3); MMQ(7, 3, 2); MMQ(7, 3, 3);
        __builtin_amdgcn_s_setprio(0);
        BARX();
    }

#undef STAGEH
#undef LDA_
#undef LDAU_
#undef LDB_
#undef MMQ
#undef BARX
#undef LGKM0

#pragma unroll
    for (int i = 0; i < 8; i++)
#pragma unroll
        for (int j = 0; j < 4; j++)
#pragma unroll
            for (int r = 0; r < 4; r++) {
                int row = bm * 256 + wm * 128 + i * 16 + quad * 4 + r;
                int ct  = bn * 256 + wn * 64 + j * 16 + m16;
                CT* dst = C + (size_t)(ct >> 12) * cstride + (size_t)row * DIM + (ct & 4095);
                if constexpr (std::is_same<CT, float>::value)
                    *dst = acc[i][j][r];
                else
                    *dst = __float2bfloat16(acc[i][j][r]);
            }
}

// ---------------------------------------------------------------------------
// Fallback GEMM (fp32 B with in-loop conversion) — used only if ws_size is
// too small for the bf16-conversion buffers.
// ---------------------------------------------------------------------------
template <typename AT, typename CT>
__global__ __launch_bounds__(256) void gemm_nat(const AT* __restrict__ A,
                                                const float* __restrict__ B,
                                                CT* __restrict__ C,
                                                int M, int N, int K) {
    __shared__ short As[128][40];
    __shared__ short Bs[128][40];
    const int tid  = threadIdx.x;
    const int lane = tid & 63;
    const int w    = tid >> 6;
    const int m16  = lane & 15;
    const int quad = lane >> 4;
    const int wm   = w >> 1, wn = w & 1;
    const int bm   = blockIdx.y, bn = blockIdx.x;

    const AT* Ab = A + (size_t)bm * 128 * K;

    f4v acc[4][4] = {};
    const int r0 = tid >> 2;
    const int kc = (tid & 3) * 8;

    for (int k0 = 0; k0 < K; k0 += 32) {
        if constexpr (std::is_same<AT, float>::value) {
#pragma unroll
            for (int half = 0; half < 2; half++) {
                const float* src = Ab + (size_t)(r0 + 64 * half) * K + k0 + kc;
                float4 f0 = *(const float4*)(src);
                float4 f1 = *(const float4*)(src + 4);
                s8v t;
                t[0] = f2bs(f0.x); t[1] = f2bs(f0.y); t[2] = f2bs(f0.z); t[3] = f2bs(f0.w);
                t[4] = f2bs(f1.x); t[5] = f2bs(f1.y); t[6] = f2bs(f1.z); t[7] = f2bs(f1.w);
                *(s8v*)&As[r0 + 64 * half][kc] = t;
            }
        } else {
            *(s8v*)&As[r0][kc]      = *(const s8v*)(Ab + (size_t)r0 * K + k0 + kc);
            *(s8v*)&As[r0 + 64][kc] = *(const s8v*)(Ab + (size_t)(r0 + 64) * K + k0 + kc);
        }
#pragma unroll
        for (int v = tid; v < 512; v += 256) {
            int kr = v >> 4;
            int nc = (v & 15) * 8;
            const float* src = B + (size_t)(k0 + kr) * N + bn * 128 + nc;
            float4 f0 = *(const float4*)(src);
            float4 f1 = *(const float4*)(src + 4);
            Bs[nc + 0][kr] = f2bs(f0.x); Bs[nc + 1][kr] = f2bs(f0.y);
            Bs[nc + 2][kr] = f2bs(f0.z); Bs[nc + 3][kr] = f2bs(f0.w);
            Bs[nc + 4][kr] = f2bs(f1.x); Bs[nc + 5][kr] = f2bs(f1.y);
            Bs[nc + 6][kr] = f2bs(f1.z); Bs[nc + 7][kr] = f2bs(f1.w);
        }
        __syncthreads();

        s8v a[4], b[4];
#pragma unroll
        for (int i = 0; i < 4; i++) a[i] = *(s8v*)&As[wm * 64 + i * 16 + m16][quad * 8];
#pragma unroll
        for (int j = 0; j < 4; j++) b[j] = *(s8v*)&Bs[wn * 64 + j * 16 + m16][quad * 8];
#pragma unroll
        for (int i = 0; i < 4; i++)
#pragma unroll
            for (int j = 0; j < 4; j++) acc[i][j] = MFMA16(a[i], b[j], acc[i][j]);
        __syncthreads();
    }

#pragma unroll
    for (int i = 0; i < 4; i++)
#pragma unroll
        for (int j = 0; j < 4; j++)
#pragma unroll
            for (int r = 0; r < 4; r++) {
                int row = bm * 128 + wm * 64 + i * 16 + quad * 4 + r;
                int col = bn * 128 + wn * 64 + j * 16 + m16;
                if constexpr (std::is_same<CT, float>::value)
                    C[(size_t)row * N + col] = acc[i][j][r];
                else
                    C[(size_t)row * N + col] = __float2bfloat16(acc[i][j][r]);
            }
}

// ---------------------------------------------------------------------------
// RoPE in-place on bf16 Q and K; freqs fp32.
// ---------------------------------------------------------------------------
__global__ void rope_kernel(bf16* __restrict__ Q, bf16* __restrict__ K,
                            const float* __restrict__ fc, const float* __restrict__ fs) {
    int tid = blockIdx.x * blockDim.x + threadIdx.x;
    int s = tid >> 11;
    int r = tid & 2047;
    int i = r & 63;
    float c  = fc[s * 64 + i];
    float sn = fs[s * 64 + i];
    size_t idx = (size_t)s * DIM + 2 * r;
    float qre = __bfloat162float(Q[idx]), qim = __bfloat162float(Q[idx + 1]);
    Q[idx]     = __float2bfloat16(qre * c - qim * sn);
    Q[idx + 1] = __float2bfloat16(qre * sn + qim * c);
    float kre = __bfloat162float(K[idx]), kim = __bfloat162float(K[idx + 1]);
    K[idx]     = __float2bfloat16(kre * c - kim * sn);
    K[idx + 1] = __float2bfloat16(kre * sn + kim * c);
}

// ---------------------------------------------------------------------------
// Flash attention (causal), PAIRED for load balance (unchanged from R4).
// Grid: (16 pairs, 32 heads) = 512 uniform blocks (33 iters each).
// ---------------------------------------------------------------------------
__global__ __launch_bounds__(256) void attn_kernel(const bf16* __restrict__ Q,
                                                   const bf16* __restrict__ K,
                                                   const bf16* __restrict__ V,
                                                   bf16* __restrict__ O) {
    __shared__ short Ks[64][136];
    __shared__ short Vs[128][72];
    __shared__ short Ps[64][72];

    const int p  = blockIdx.x;            // pair index 0..15
    const int h  = blockIdx.y;
    const int tid  = threadIdx.x;
    const int w    = tid >> 6;
    const int lane = tid & 63;
    const int m16  = lane & 15;
    const int quad = lane >> 4;
    const float scale = 0.08838834764831845f;   // 1/sqrt(128)
    const int NQB = (int)gridDim.x * 2;   // 32 q-tiles

    const int rn  = tid >> 4;            // 0..15
    const int rc  = (tid & 15) * 8;      // 0,8,...,120
    const int dcs = (tid & 15) & 7;      // = (rc>>3)&7, V write swizzle term

    for (int half = 0; half < 2; half++) {
        const int qb = half ? (NQB - 1 - p) : p;

        s8v aq[4];
        {
            const bf16* qp = Q + (size_t)(qb * 64 + w * 16 + m16) * DIM + h * HD + quad * 8;
#pragma unroll
            for (int ks = 0; ks < 4; ks++) aq[ks] = *(const s8v*)(qp + ks * 32);
        }

        f4v acc[8] = {};
        float mrow[4] = {-1e30f, -1e30f, -1e30f, -1e30f};
        float lrow[4] = {};

        // prologue: load tile 0 into regs (coalesced)
        s8v kreg[4], vreg[4];
        {
            const bf16* kp = K + (size_t)rn * DIM + h * HD + rc;
            const bf16* vp = V + (size_t)rn * DIM + h * HD + rc;
#pragma unroll
            for (int it = 0; it < 4; it++) {
                kreg[it] = *(const s8v*)(kp + (size_t)it * 16 * DIM);
                vreg[it] = *(const s8v*)(vp + (size_t)it * 16 * DIM);
            }
        }

        for (int kt = 0; kt <= qb; kt++) {
            // ---- stage regs -> LDS (K direct; V transposed w/ XOR swizzle) ----
#pragma unroll
            for (int it = 0; it < 4; it++)
                *(s8v*)&Ks[it * 16 + rn][rc] = kreg[it];
#pragma unroll
            for (int it = 0; it < 4; it++) {
                int n   = it * 16 + rn;                       // key index 0..63
                int col = (((n >> 3) ^ dcs) << 3) | (n & 7);  // swizzled column
#pragma unroll
                for (int e = 0; e < 8; e++) Vs[rc + e][col] = vreg[it][e];
            }
            __syncthreads();

            // ---- prefetch tile kt+1 ----
            if (kt < qb) {
                const bf16* kp = K + (size_t)((kt + 1) * 64 + rn) * DIM + h * HD + rc;
                const bf16* vp = V + (size_t)((kt + 1) * 64 + rn) * DIM + h * HD + rc;
#pragma unroll
                for (int it = 0; it < 4; it++) {
                    kreg[it] = *(const s8v*)(kp + (size_t)it * 16 * DIM);
                    vreg[it] = *(const s8v*)(vp + (size_t)it * 16 * DIM);
                }
            }

            // ---- QK^T ----
            f4v sc[4] = {};
#pragma unroll
            for (int j = 0; j < 4; j++)
#pragma unroll
                for (int ks = 0; ks < 4; ks++) {
                    s8v bk = *(s8v*)&Ks[j * 16 + m16][ks * 32 + quad * 8];
                    sc[j] = MFMA16(aq[ks], bk, sc[j]);
                }

            const bool diag = (kt == qb);
#pragma unroll
            for (int j = 0; j < 4; j++)
#pragma unroll
                for (int r = 0; r < 4; r++) {
                    float sv = sc[j][r] * scale;
                    if (diag && (j * 16 + m16) > (w * 16 + quad * 4 + r)) sv = -1e30f;
                    sc[j][r] = sv;
                }

            // ---- online softmax ----
#pragma unroll
            for (int r = 0; r < 4; r++) {
                float mx = fmaxf(fmaxf(sc[0][r], sc[1][r]), fmaxf(sc[2][r], sc[3][r]));
#pragma unroll
                for (int off = 1; off < 16; off <<= 1) mx = fmaxf(mx, __shfl_xor(mx, off, 64));
                float mn    = fmaxf(mrow[r], mx);
                float alpha = __expf(mrow[r] - mn);
                mrow[r] = mn;
                float rs = 0.f;
#pragma unroll
                for (int j = 0; j < 4; j++) {
                    float pj = __expf(sc[j][r] - mn);
                    sc[j][r] = pj;
                    rs += pj;
                }
#pragma unroll
                for (int off = 1; off < 16; off <<= 1) rs += __shfl_xor(rs, off, 64);
                lrow[r] = lrow[r] * alpha + rs;
#pragma unroll
                for (int jo = 0; jo < 8; jo++) acc[jo][r] = acc[jo][r] * alpha;
            }

            // ---- P store (wave-private rows -> no block barrier needed) ----
#pragma unroll
            for (int j = 0; j < 4; j++)
#pragma unroll
                for (int r = 0; r < 4; r++)
                    Ps[w * 16 + quad * 4 + r][j * 16 + m16] = f2bs(sc[j][r]);
            asm volatile("s_waitcnt lgkmcnt(0)" ::: "memory");
            __builtin_amdgcn_sched_barrier(0);

            // ---- PV (Vs read through the same XOR swizzle) ----
#pragma unroll
            for (int ks2 = 0; ks2 < 2; ks2++) {
                s8v ap = *(s8v*)&Ps[w * 16 + m16][ks2 * 32 + quad * 8];
#pragma unroll
                for (int jo = 0; jo < 8; jo++) {
                    int dv = jo * 16 + m16;
                    int cg = (((ks2 * 4 + quad) ^ ((dv >> 3) & 7)) << 3);
                    s8v bv = *(s8v*)&Vs[dv][cg];
                    acc[jo] = MFMA16(ap, bv, acc[jo]);
                }
            }
            __syncthreads();
        }

#pragma unroll
        for (int jo = 0; jo < 8; jo++)
#pragma unroll
            for (int r = 0; r < 4; r++) {
                float o = acc[jo][r] / fmaxf(lrow[r], 1e-30f);
                int row = qb * 64 + w * 16 + quad * 4 + r;
                int col = h * HD + jo * 16 + m16;
                O[(size_t)row * DIM + col] = __float2bfloat16(o);
            }
    }
}

// ---------------------------------------------------------------------------
extern "C" void kernel_launch(void* const* d_in, const int* in_sizes, int n_in,
                              void* d_out, int out_size, void* d_ws, size_t ws_size,
                              hipStream_t stream) {
    const float* x  = (const float*)d_in[0];
    const float* wq = (const float*)d_in[1];
    const float* wk = (const float*)d_in[2];
    const float* wv = (const float*)d_in[3];
    const float* wo = (const float*)d_in[4];
    const float* fc = (const float*)d_in[5];
    const float* fs = (const float*)d_in[6];

    float* out = (float*)d_out;

    const size_t SZ = (size_t)SEQ * DIM;
    const size_t WZ = (size_t)DIM * DIM;
    bf16* Q  = (bf16*)d_ws;
    bf16* Kb = Q + SZ;      // Q,Kb,V contiguous -> fused-GEMM C via cstride=SZ
    bf16* V  = Kb + SZ;
    bf16* AO = V + SZ;

    const size_t needF = (5 * SZ + 3 * WZ) * sizeof(bf16);  // ~185 MB (fused QKV)
    const size_t needU = (5 * SZ + WZ) * sizeof(bf16);      // ~117 MB

    dim3 tGw(DIM / 64, DIM / 64);

    if (ws_size >= needF) {
        bf16* xb = AO + SZ;        // [SEQ][DIM] bf16
        bf16* wb = xb + SZ;        // [3*DIM][DIM] bf16 stacked wq^T|wk^T|wv^T

        convert_bf16<<<(int)(SZ / 4 / 256), 256, 0, stream>>>(x, xb);
        convt_bf16<<<tGw, 256, 0, stream>>>(wq, wb, DIM, DIM);
        convt_bf16<<<tGw, 256, 0, stream>>>(wk, wb + WZ, DIM, DIM);
        convt_bf16<<<tGw, 256, 0, stream>>>(wv, wb + 2 * WZ, DIM, DIM);

        // fused QKV: N=12288, grid (48,8)=384 blocks; C buffer-select by col>>12
        gemm_256<bf16><<<dim3(3 * DIM / 256, SEQ / 256), 512, 0, stream>>>(
            xb, wb, Q, DIM, SZ);

        rope_kernel<<<(SEQ * (DIM / 2)) / 256, 256, 0, stream>>>(Q, Kb, fc, fs);
        attn_kernel<<<dim3(SEQ / 128, NH), 256, 0, stream>>>(Q, Kb, V, AO);

        convt_bf16<<<tGw, 256, 0, stream>>>(wo, wb, DIM, DIM);
        gemm_256<float><<<dim3(DIM / 256, SEQ / 256), 512, 0, stream>>>(
            AO, wb, out, DIM, 0);
    } else if (ws_size >= needU) {
        bf16* xb = AO + SZ;
        bf16* wb = xb + SZ;        // [DIM][DIM] bf16, reused per weight

        dim3 gU(DIM / 256, SEQ / 256);   // (16,8) = 128 blocks

        convert_bf16<<<(int)(SZ / 4 / 256), 256, 0, stream>>>(x, xb);

        convt_bf16<<<tGw, 256, 0, stream>>>(wq, wb, DIM, DIM);
        gemm_256<bf16><<<gU, 512, 0, stream>>>(xb, wb, Q, DIM, 0);
        convt_bf16<<<tGw, 256, 0, stream>>>(wk, wb, DIM, DIM);
        gemm_256<bf16><<<gU, 512, 0, stream>>>(xb, wb, Kb, DIM, 0);
        convt_bf16<<<tGw, 256, 0, stream>>>(wv, wb, DIM, DIM);
        gemm_256<bf16><<<gU, 512, 0, stream>>>(xb, wb, V, DIM, 0);

        rope_kernel<<<(SEQ * (DIM / 2)) / 256, 256, 0, stream>>>(Q, Kb, fc, fs);
        attn_kernel<<<dim3(SEQ / 128, NH), 256, 0, stream>>>(Q, Kb, V, AO);

        convt_bf16<<<tGw, 256, 0, stream>>>(wo, wb, DIM, DIM);
        gemm_256<float><<<gU, 512, 0, stream>>>(AO, wb, out, DIM, 0);
    } else {
        dim3 gGn(DIM / 128, SEQ / 128);
        gemm_nat<float, bf16><<<gGn, 256, 0, stream>>>(x, wq, Q,  SEQ, DIM, DIM);
        gemm_nat<float, bf16><<<gGn, 256, 0, stream>>>(x, wk, Kb, SEQ, DIM, DIM);
        gemm_nat<float, bf16><<<gGn, 256, 0, stream>>>(x, wv, V,  SEQ, DIM, DIM);
        rope_kernel<<<(SEQ * (DIM / 2)) / 256, 256, 0, stream>>>(Q, Kb, fc, fs);
        attn_kernel<<<dim3(SEQ / 128, NH), 256, 0, stream>>>(Q, Kb, V, AO);
        gemm_nat<bf16, float><<<gGn, 256, 0, stream>>>(AO, wo, out, SEQ, DIM, DIM);
    }
}

// Round 6
// 779.474 us; speedup vs baseline: 1.0545x; 1.0545x over previous
//
#include <hip/hip_runtime.h>
#include <hip/hip_bf16.h>
#include <type_traits>

typedef __hip_bfloat16 bf16;
typedef __attribute__((ext_vector_type(8))) short s8v;   // 8 x bf16 (16B)
typedef __attribute__((ext_vector_type(4))) short s4v;   // 4 x bf16 (8B)
typedef __attribute__((ext_vector_type(4))) float f4v;   // MFMA C/D frag

#define MFMA16(A, B, C) __builtin_amdgcn_mfma_f32_16x16x32_bf16((A), (B), (C), 0, 0, 0)

constexpr int SEQ = 2048;
constexpr int DIM = 4096;
constexpr int NH  = 32;
constexpr int HD  = 128;

__device__ __forceinline__ short f2bs(float f) {
    __hip_bfloat16_raw r = __float2bfloat16(f);
    return (short)r.x;
}

// async global->LDS, 16B per lane. HW semantics: wave-uniform LDS base +
// lane*16; lane i's global data lands at base + i*16.
__device__ __forceinline__ void ld_g2l(const bf16* g, bf16* l) {
    __builtin_amdgcn_global_load_lds(
        (const __attribute__((address_space(1))) void*)g,
        (__attribute__((address_space(3))) void*)l, 16, 0, 0);
}

// ---------------------------------------------------------------------------
// fp32 -> bf16 elementwise convert (float4 loads)
// ---------------------------------------------------------------------------
__global__ void convert_bf16(const float* __restrict__ s, bf16* __restrict__ d) {
    int i = blockIdx.x * blockDim.x + threadIdx.x;
    float4 f = ((const float4*)s)[i];
    s4v o;
    o[0] = f2bs(f.x); o[1] = f2bs(f.y); o[2] = f2bs(f.z); o[3] = f2bs(f.w);
    *(s4v*)(d + (size_t)i * 4) = o;
}

// ---------------------------------------------------------------------------
// fp32 [R][C] -> bf16 [C][R] transpose + convert, vectorized both sides.
// ---------------------------------------------------------------------------
__global__ __launch_bounds__(256) void convt_bf16(const float* __restrict__ src,
                                                  bf16* __restrict__ dst,
                                                  int R, int C) {
    __shared__ float t[64][65];
    const int c0 = blockIdx.x * 64, r0 = blockIdx.y * 64;
    const int tid = threadIdx.x;
    const int lr = tid >> 4;             // 0..15
    const int lc = (tid & 15) * 4;       // 0..60
#pragma unroll
    for (int i = 0; i < 4; i++) {
        float4 f = *(const float4*)(src + (size_t)(r0 + lr + 16 * i) * C + c0 + lc);
        t[lr + 16 * i][lc]     = f.x;
        t[lr + 16 * i][lc + 1] = f.y;
        t[lr + 16 * i][lc + 2] = f.z;
        t[lr + 16 * i][lc + 3] = f.w;
    }
    __syncthreads();
    const int oc = tid >> 2;             // output row (source col) 0..63
#pragma unroll
    for (int i = 0; i < 2; i++) {
        int rr = (tid & 3) * 8 + 32 * i; // 0..56 step 8
        s8v o;
#pragma unroll
        for (int e = 0; e < 8; e++) o[e] = f2bs(t[rr + e][oc]);
        *(s8v*)(dst + (size_t)(c0 + oc) * R + r0 + rr) = o;
    }
}

// ---------------------------------------------------------------------------
// Register-pipelined 256xBN GEMM. C = A[M,K]*Bt[N,K]^T, bf16 in, CT out.
//   BM=256, BN=NJ*64 (NJ=4: 256, NJ=2: 128), BK=64. 512 thr = 8 waves
//   (2M x 4N), per-wave 128 x NJ*16. LDS dbuf: NJ=4 128KB, NJ=2 96KB.
//
// Pipeline (fix for R5's read/MFMA alternation, MfmaUtil 29%):
//   B frags (NJ*2 s8v) read ONCE per tile, live whole tile. A read in
//   m-pairs ONE PHASE AHEAD with counted lgkmcnt(2) -> each phase's 2*NJ
//   MFMA overlap the next phase's ds_reads. 2 barriers/tile.
// Per tile t (cur=t&1):
//   ph0..ph6: issue A(m_{i+1}) (2 reads, ping-pong reg slot);
//             lgkmcnt(2) [in-order DS: drains all prior]; 2*NJ MFMA m_i.
//   ph7: lgkmcnt(0) [drain A(m7), last reads of cur];
//        BARRIER#1 [all waves' reads of cur executed -> stage-safe];
//        stage t+2 -> cur (LPT loads); MFMA m7 (reg-only, covers latency);
//        vmcnt(LPT) [t+1's LPT loads landed, in-order retire];
//        BARRIER#2 [publish: ALL waves' t+1 loads landed];
//        issue next tile's B (NJ*2) + A(m0) (2) from buf cur^1.
// Hazard proofs:
//  * stage(t+2)->cur vs reads of cur: every read of cur (B+A0 issued at end
//    of t-1, drained by ph0's lgkmcnt(2); A1..A7 in ph0..ph6, drained by
//    ph7's lgkmcnt(0)) is EXECUTED before the wave reaches BARRIER#1; stage
//    issued after -> safe.
//  * next-tile reads vs staging: vmcnt counts only the OWN wave's loads, so
//    BARRIER#2 after every wave's vmcnt(LPT) is REQUIRED before any wave
//    reads another wave's staged region. reads come after BARRIER#2 -> safe.
//  * WAR on bF: next-tile B reads issue AFTER MFMA m7 in program order;
//    compiler/HW preserve reg dependence -> m7 consumes old values.
//  * vm in-flight at vmcnt: t+1's LPT + t+2's LPT = 2*LPT -> wait to LPT
//    retires t+1's (in-order) exactly.
// Swizzle (verified R2-R5, bank-conflict 0): 16B-group g=(byte>>4)&7 holds
//   global group g^(row&7); LINEAR LDS dest, permutation on per-lane GLOBAL
//   source (rule #21); reads XOR the same term.
// XCD 2D chunk (fix for FETCH=409MB): XCD j owns ALL 8 bm x bn in
//   [j*cpx,(j+1)*cpx), cpx=NBN/8 -> per-XCD unique traffic A 16MB + B
//   2MB*cpx (vs 102MB with row-per-XCD). Requires NBN%8==0 (48/32/16 ok).
// ---------------------------------------------------------------------------
template <int NJ, typename CT>
__global__ __launch_bounds__(512, 2) void gemm_pipe(const bf16* __restrict__ A,
                                                    const bf16* __restrict__ Bt,
                                                    CT* __restrict__ C,
                                                    int K, size_t cstride) {
    constexpr int BN = NJ * 64;
    __shared__ bf16 As_[2][256 * 64];
    __shared__ bf16 Bs_[2][BN * 64];
    const int tid  = threadIdx.x;
    const int lane = tid & 63;
    const int wv   = tid >> 6;
    const int m16  = lane & 15;
    const int quad = lane >> 4;
    const int wm   = wv >> 2, wn = wv & 3;   // 2M x 4N wave grid

    // ---- XCD 2D chunk remap ----
    const int NBN = (int)gridDim.x;
    const int cpx = NBN >> 3;
    const int lin = (int)(blockIdx.y * gridDim.x + blockIdx.x);
    const int s_  = lin >> 3;
    const int bm  = s_ / cpx;                 // bnl fastest: A panel shared
    const int bn  = (lin & 7) * cpx + (s_ - bm * cpx);

    const bf16* Ab = A  + (size_t)bm * 256 * K;
    const bf16* Bb = Bt + (size_t)bn * BN * K;

    // staging geometry: STAGEH = 128 rows x 64 cols (2 loads/thread)
    const int row0 = tid >> 3;                       // 0..63
    const int gc8  = ((tid & 7) ^ (row0 & 7)) * 8;   // inverse-swizzled src
    const int dst0 = wv * 512;                       // elems; +lane*8 by HW
    const int dst1 = 4096 + wv * 512;

    // read geometry
    const int aB  = (wm * 128 + m16) * 64;
    const int bB  = (wn * (NJ * 16) + m16) * 64;
    const int swz = m16 & 7;
    const int c0k = ((0 + quad) ^ swz) * 8;   // ks=0 col offset (bf16 units)
    const int c1k = ((4 + quad) ^ swz) * 8;   // ks=1

    const int NT = K >> 6;

    f4v acc[8][NJ] = {};
    s8v aF[2][2];        // A m-pair ping-pong [slot][ks]
    s8v bF[NJ][2];       // B whole tile      [j][ks]

#define STAGEH(gb, lb) do { \
        ld_g2l((gb) + (size_t)row0 * K + gc8, (lb) + dst0); \
        ld_g2l((gb) + (size_t)(row0 + 64) * K + gc8, (lb) + dst1); } while (0)
#define STA(k0, buf) do { \
        STAGEH(Ab + (k0), As_[buf]); \
        STAGEH(Ab + (size_t)128 * K + (k0), As_[buf] + 8192); } while (0)
#define STB(k0, buf) do { \
        STAGEH(Bb + (k0), Bs_[buf]); \
        if constexpr (NJ == 4) { \
            STAGEH(Bb + (size_t)128 * K + (k0), Bs_[buf] + 8192); } } while (0)
#define WAIT_VM_N() do { \
        if constexpr (NJ == 4) asm volatile("s_waitcnt vmcnt(8)" ::: "memory"); \
        else                   asm volatile("s_waitcnt vmcnt(6)" ::: "memory"); \
        __builtin_amdgcn_sched_barrier(0); } while (0)
#define ISSUE_NEXT(nb) do { \
        _Pragma("unroll") \
        for (int j = 0; j < NJ; ++j) { \
            bF[j][0] = *(const s8v*)(Bs_[nb] + bB + j * 1024 + c0k); \
            bF[j][1] = *(const s8v*)(Bs_[nb] + bB + j * 1024 + c1k); } \
        aF[0][0] = *(const s8v*)(As_[nb] + aB + c0k); \
        aF[0][1] = *(const s8v*)(As_[nb] + aB + c1k); } while (0)

    // ---- prologue: stage t0+t1; wait t0 landed; publish; issue t0 frags ----
    STA(0, 0); STB(0, 0);
    STA(64, 1); STB(64, 1);
    WAIT_VM_N();
    __builtin_amdgcn_s_barrier();
    ISSUE_NEXT(0);
    // invariant entering each tile: lgkm outstanding = NJ*2+2 (B + A m0)

    for (int t = 0; t < NT; ++t) {
        const int cur = t & 1;
        const bf16* Ac = As_[cur];

        // ---- ph0..ph6: A-pair lookahead, counted lgkm, MFMA overlap ----
#pragma unroll
        for (int i = 0; i < 7; ++i) {
            aF[(i + 1) & 1][0] = *(const s8v*)(Ac + aB + (i + 1) * 1024 + c0k);
            aF[(i + 1) & 1][1] = *(const s8v*)(Ac + aB + (i + 1) * 1024 + c1k);
            asm volatile("s_waitcnt lgkmcnt(2)" ::: "memory");
            __builtin_amdgcn_sched_barrier(0);
            __builtin_amdgcn_s_setprio(1);
#pragma unroll
            for (int j = 0; j < NJ; ++j) {
                acc[i][j] = MFMA16(aF[i & 1][0], bF[j][0], acc[i][j]);
                acc[i][j] = MFMA16(aF[i & 1][1], bF[j][1], acc[i][j]);
            }
            __builtin_amdgcn_s_setprio(0);
        }

        // ---- ph7 ----
        asm volatile("s_waitcnt lgkmcnt(0)" ::: "memory");
        __builtin_amdgcn_sched_barrier(0);
        __builtin_amdgcn_s_barrier();                 // BARRIER#1
        const bool more = (t + 2 < NT);
        if (more) {
            const int k2 = (t + 2) << 6;
            STA(k2, cur); STB(k2, cur);
        }
        __builtin_amdgcn_s_setprio(1);
#pragma unroll
        for (int j = 0; j < NJ; ++j) {                // MFMA m7 (reg-only)
            acc[7][j] = MFMA16(aF[1][0], bF[j][0], acc[7][j]);
            acc[7][j] = MFMA16(aF[1][1], bF[j][1], acc[7][j]);
        }
        __builtin_amdgcn_s_setprio(0);
        if (more) {
            WAIT_VM_N();
        } else if (t + 1 < NT) {
            asm volatile("s_waitcnt vmcnt(0)" ::: "memory");
            __builtin_amdgcn_sched_barrier(0);
        }
        if (t + 1 < NT) {
            __builtin_amdgcn_s_barrier();             // BARRIER#2 (publish)
            ISSUE_NEXT(cur ^ 1);
        }
    }

#undef STAGEH
#undef STA
#undef STB
#undef WAIT_VM_N
#undef ISSUE_NEXT

#pragma unroll
    for (int i = 0; i < 8; i++)
#pragma unroll
        for (int j = 0; j < NJ; j++)
#pragma unroll
            for (int r = 0; r < 4; r++) {
                int row = bm * 256 + wm * 128 + i * 16 + quad * 4 + r;
                int ct  = bn * BN + wn * (NJ * 16) + j * 16 + m16;
                CT* dst = C + (size_t)(ct >> 12) * cstride + (size_t)row * DIM + (ct & 4095);
                if constexpr (std::is_same<CT, float>::value)
                    *dst = acc[i][j][r];
                else
                    *dst = __float2bfloat16(acc[i][j][r]);
            }
}

// ---------------------------------------------------------------------------
// Fallback GEMM (fp32 B with in-loop conversion) — used only if ws_size is
// too small for the bf16-conversion buffers.
// ---------------------------------------------------------------------------
template <typename AT, typename CT>
__global__ __launch_bounds__(256) void gemm_nat(const AT* __restrict__ A,
                                                const float* __restrict__ B,
                                                CT* __restrict__ C,
                                                int M, int N, int K) {
    __shared__ short As[128][40];
    __shared__ short Bs[128][40];
    const int tid  = threadIdx.x;
    const int lane = tid & 63;
    const int w    = tid >> 6;
    const int m16  = lane & 15;
    const int quad = lane >> 4;
    const int wm   = w >> 1, wn = w & 1;
    const int bm   = blockIdx.y, bn = blockIdx.x;

    const AT* Ab = A + (size_t)bm * 128 * K;

    f4v acc[4][4] = {};
    const int r0 = tid >> 2;
    const int kc = (tid & 3) * 8;

    for (int k0 = 0; k0 < K; k0 += 32) {
        if constexpr (std::is_same<AT, float>::value) {
#pragma unroll
            for (int half = 0; half < 2; half++) {
                const float* src = Ab + (size_t)(r0 + 64 * half) * K + k0 + kc;
                float4 f0 = *(const float4*)(src);
                float4 f1 = *(const float4*)(src + 4);
                s8v t;
                t[0] = f2bs(f0.x); t[1] = f2bs(f0.y); t[2] = f2bs(f0.z); t[3] = f2bs(f0.w);
                t[4] = f2bs(f1.x); t[5] = f2bs(f1.y); t[6] = f2bs(f1.z); t[7] = f2bs(f1.w);
                *(s8v*)&As[r0 + 64 * half][kc] = t;
            }
        } else {
            *(s8v*)&As[r0][kc]      = *(const s8v*)(Ab + (size_t)r0 * K + k0 + kc);
            *(s8v*)&As[r0 + 64][kc] = *(const s8v*)(Ab + (size_t)(r0 + 64) * K + k0 + kc);
        }
#pragma unroll
        for (int v = tid; v < 512; v += 256) {
            int kr = v >> 4;
            int nc = (v & 15) * 8;
            const float* src = B + (size_t)(k0 + kr) * N + bn * 128 + nc;
            float4 f0 = *(const float4*)(src);
            float4 f1 = *(const float4*)(src + 4);
            Bs[nc + 0][kr] = f2bs(f0.x); Bs[nc + 1][kr] = f2bs(f0.y);
            Bs[nc + 2][kr] = f2bs(f0.z); Bs[nc + 3][kr] = f2bs(f0.w);
            Bs[nc + 4][kr] = f2bs(f1.x); Bs[nc + 5][kr] = f2bs(f1.y);
            Bs[nc + 6][kr] = f2bs(f1.z); Bs[nc + 7][kr] = f2bs(f1.w);
        }
        __syncthreads();

        s8v a[4], b[4];
#pragma unroll
        for (int i = 0; i < 4; i++) a[i] = *(s8v*)&As[wm * 64 + i * 16 + m16][quad * 8];
#pragma unroll
        for (int j = 0; j < 4; j++) b[j] = *(s8v*)&Bs[wn * 64 + j * 16 + m16][quad * 8];
#pragma unroll
        for (int i = 0; i < 4; i++)
#pragma unroll
            for (int j = 0; j < 4; j++) acc[i][j] = MFMA16(a[i], b[j], acc[i][j]);
        __syncthreads();
    }

#pragma unroll
    for (int i = 0; i < 4; i++)
#pragma unroll
        for (int j = 0; j < 4; j++)
#pragma unroll
            for (int r = 0; r < 4; r++) {
                int row = bm * 128 + wm * 64 + i * 16 + quad * 4 + r;
                int col = bn * 128 + wn * 64 + j * 16 + m16;
                if constexpr (std::is_same<CT, float>::value)
                    C[(size_t)row * N + col] = acc[i][j][r];
                else
                    C[(size_t)row * N + col] = __float2bfloat16(acc[i][j][r]);
            }
}

// ---------------------------------------------------------------------------
// RoPE in-place on bf16 Q and K; freqs fp32.
// ---------------------------------------------------------------------------
__global__ void rope_kernel(bf16* __restrict__ Q, bf16* __restrict__ K,
                            const float* __restrict__ fc, const float* __restrict__ fs) {
    int tid = blockIdx.x * blockDim.x + threadIdx.x;
    int s = tid >> 11;
    int r = tid & 2047;
    int i = r & 63;
    float c  = fc[s * 64 + i];
    float sn = fs[s * 64 + i];
    size_t idx = (size_t)s * DIM + 2 * r;
    float qre = __bfloat162float(Q[idx]), qim = __bfloat162float(Q[idx + 1]);
    Q[idx]     = __float2bfloat16(qre * c - qim * sn);
    Q[idx + 1] = __float2bfloat16(qre * sn + qim * c);
    float kre = __bfloat162float(K[idx]), kim = __bfloat162float(K[idx + 1]);
    K[idx]     = __float2bfloat16(kre * c - kim * sn);
    K[idx + 1] = __float2bfloat16(kre * sn + kim * c);
}

// ---------------------------------------------------------------------------
// Flash attention (causal), PAIRED for load balance (unchanged from R4).
// Grid: (16 pairs, 32 heads) = 512 uniform blocks (33 iters each).
// ---------------------------------------------------------------------------
__global__ __launch_bounds__(256) void attn_kernel(const bf16* __restrict__ Q,
                                                   const bf16* __restrict__ K,
                                                   const bf16* __restrict__ V,
                                                   bf16* __restrict__ O) {
    __shared__ short Ks[64][136];
    __shared__ short Vs[128][72];
    __shared__ short Ps[64][72];

    const int p  = blockIdx.x;            // pair index 0..15
    const int h  = blockIdx.y;
    const int tid  = threadIdx.x;
    const int w    = tid >> 6;
    const int lane = tid & 63;
    const int m16  = lane & 15;
    const int quad = lane >> 4;
    const float scale = 0.08838834764831845f;   // 1/sqrt(128)
    const int NQB = (int)gridDim.x * 2;   // 32 q-tiles

    const int rn  = tid >> 4;            // 0..15
    const int rc  = (tid & 15) * 8;      // 0,8,...,120
    const int dcs = (tid & 15) & 7;      // = (rc>>3)&7, V write swizzle term

    for (int half = 0; half < 2; half++) {
        const int qb = half ? (NQB - 1 - p) : p;

        s8v aq[4];
        {
            const bf16* qp = Q + (size_t)(qb * 64 + w * 16 + m16) * DIM + h * HD + quad * 8;
#pragma unroll
            for (int ks = 0; ks < 4; ks++) aq[ks] = *(const s8v*)(qp + ks * 32);
        }

        f4v acc[8] = {};
        float mrow[4] = {-1e30f, -1e30f, -1e30f, -1e30f};
        float lrow[4] = {};

        // prologue: load tile 0 into regs (coalesced)
        s8v kreg[4], vreg[4];
        {
            const bf16* kp = K + (size_t)rn * DIM + h * HD + rc;
            const bf16* vp = V + (size_t)rn * DIM + h * HD + rc;
#pragma unroll
            for (int it = 0; it < 4; it++) {
                kreg[it] = *(const s8v*)(kp + (size_t)it * 16 * DIM);
                vreg[it] = *(const s8v*)(vp + (size_t)it * 16 * DIM);
            }
        }

        for (int kt = 0; kt <= qb; kt++) {
            // ---- stage regs -> LDS (K direct; V transposed w/ XOR swizzle) ----
#pragma unroll
            for (int it = 0; it < 4; it++)
                *(s8v*)&Ks[it * 16 + rn][rc] = kreg[it];
#pragma unroll
            for (int it = 0; it < 4; it++) {
                int n   = it * 16 + rn;                       // key index 0..63
                int col = (((n >> 3) ^ dcs) << 3) | (n & 7);  // swizzled column
#pragma unroll
                for (int e = 0; e < 8; e++) Vs[rc + e][col] = vreg[it][e];
            }
            __syncthreads();

            // ---- prefetch tile kt+1 ----
            if (kt < qb) {
                const bf16* kp = K + (size_t)((kt + 1) * 64 + rn) * DIM + h * HD + rc;
                const bf16* vp = V + (size_t)((kt + 1) * 64 + rn) * DIM + h * HD + rc;
#pragma unroll
                for (int it = 0; it < 4; it++) {
                    kreg[it] = *(const s8v*)(kp + (size_t)it * 16 * DIM);
                    vreg[it] = *(const s8v*)(vp + (size_t)it * 16 * DIM);
                }
            }

            // ---- QK^T ----
            f4v sc[4] = {};
#pragma unroll
            for (int j = 0; j < 4; j++)
#pragma unroll
                for (int ks = 0; ks < 4; ks++) {
                    s8v bk = *(s8v*)&Ks[j * 16 + m16][ks * 32 + quad * 8];
                    sc[j] = MFMA16(aq[ks], bk, sc[j]);
                }

            const bool diag = (kt == qb);
#pragma unroll
            for (int j = 0; j < 4; j++)
#pragma unroll
                for (int r = 0; r < 4; r++) {
                    float sv = sc[j][r] * scale;
                    if (diag && (j * 16 + m16) > (w * 16 + quad * 4 + r)) sv = -1e30f;
                    sc[j][r] = sv;
                }

            // ---- online softmax ----
#pragma unroll
            for (int r = 0; r < 4; r++) {
                float mx = fmaxf(fmaxf(sc[0][r], sc[1][r]), fmaxf(sc[2][r], sc[3][r]));
#pragma unroll
                for (int off = 1; off < 16; off <<= 1) mx = fmaxf(mx, __shfl_xor(mx, off, 64));
                float mn    = fmaxf(mrow[r], mx);
                float alpha = __expf(mrow[r] - mn);
                mrow[r] = mn;
                float rs = 0.f;
#pragma unroll
                for (int j = 0; j < 4; j++) {
                    float pj = __expf(sc[j][r] - mn);
                    sc[j][r] = pj;
                    rs += pj;
                }
#pragma unroll
                for (int off = 1; off < 16; off <<= 1) rs += __shfl_xor(rs, off, 64);
                lrow[r] = lrow[r] * alpha + rs;
#pragma unroll
                for (int jo = 0; jo < 8; jo++) acc[jo][r] = acc[jo][r] * alpha;
            }

            // ---- P store (wave-private rows -> no block barrier needed) ----
#pragma unroll
            for (int j = 0; j < 4; j++)
#pragma unroll
                for (int r = 0; r < 4; r++)
                    Ps[w * 16 + quad * 4 + r][j * 16 + m16] = f2bs(sc[j][r]);
            asm volatile("s_waitcnt lgkmcnt(0)" ::: "memory");
            __builtin_amdgcn_sched_barrier(0);

            // ---- PV (Vs read through the same XOR swizzle) ----
#pragma unroll
            for (int ks2 = 0; ks2 < 2; ks2++) {
                s8v ap = *(s8v*)&Ps[w * 16 + m16][ks2 * 32 + quad * 8];
#pragma unroll
                for (int jo = 0; jo < 8; jo++) {
                    int dv = jo * 16 + m16;
                    int cg = (((ks2 * 4 + quad) ^ ((dv >> 3) & 7)) << 3);
                    s8v bv = *(s8v*)&Vs[dv][cg];
                    acc[jo] = MFMA16(ap, bv, acc[jo]);
                }
            }
            __syncthreads();
        }

#pragma unroll
        for (int jo = 0; jo < 8; jo++)
#pragma unroll
            for (int r = 0; r < 4; r++) {
                float o = acc[jo][r] / fmaxf(lrow[r], 1e-30f);
                int row = qb * 64 + w * 16 + quad * 4 + r;
                int col = h * HD + jo * 16 + m16;
                O[(size_t)row * DIM + col] = __float2bfloat16(o);
            }
    }
}

// ---------------------------------------------------------------------------
extern "C" void kernel_launch(void* const* d_in, const int* in_sizes, int n_in,
                              void* d_out, int out_size, void* d_ws, size_t ws_size,
                              hipStream_t stream) {
    const float* x  = (const float*)d_in[0];
    const float* wq = (const float*)d_in[1];
    const float* wk = (const float*)d_in[2];
    const float* wv = (const float*)d_in[3];
    const float* wo = (const float*)d_in[4];
    const float* fc = (const float*)d_in[5];
    const float* fs = (const float*)d_in[6];

    float* out = (float*)d_out;

    const size_t SZ = (size_t)SEQ * DIM;
    const size_t WZ = (size_t)DIM * DIM;
    bf16* Q  = (bf16*)d_ws;
    bf16* Kb = Q + SZ;      // Q,Kb,V contiguous -> fused-GEMM C via cstride=SZ
    bf16* V  = Kb + SZ;
    bf16* AO = V + SZ;

    const size_t needF = (5 * SZ + 3 * WZ) * sizeof(bf16);  // ~185 MB (fused QKV)
    const size_t needU = (5 * SZ + WZ) * sizeof(bf16);      // ~117 MB

    dim3 tGw(DIM / 64, DIM / 64);

    if (ws_size >= needF) {
        bf16* xb = AO + SZ;        // [SEQ][DIM] bf16
        bf16* wb = xb + SZ;        // [3*DIM][DIM] bf16 stacked wq^T|wk^T|wv^T

        convert_bf16<<<(int)(SZ / 4 / 256), 256, 0, stream>>>(x, xb);
        convt_bf16<<<tGw, 256, 0, stream>>>(wq, wb, DIM, DIM);
        convt_bf16<<<tGw, 256, 0, stream>>>(wk, wb + WZ, DIM, DIM);
        convt_bf16<<<tGw, 256, 0, stream>>>(wv, wb + 2 * WZ, DIM, DIM);

        // fused QKV: N=12288, grid (48,8); C buffer-select by col>>12
        gemm_pipe<4, bf16><<<dim3(3 * DIM / 256, SEQ / 256), 512, 0, stream>>>(
            xb, wb, Q, DIM, SZ);

        rope_kernel<<<(SEQ * (DIM / 2)) / 256, 256, 0, stream>>>(Q, Kb, fc, fs);
        attn_kernel<<<dim3(SEQ / 128, NH), 256, 0, stream>>>(Q, Kb, V, AO);

        convt_bf16<<<tGw, 256, 0, stream>>>(wo, wb, DIM, DIM);
        // WO: BN=128 -> grid (32,8)=256 blocks = full machine
        gemm_pipe<2, float><<<dim3(DIM / 128, SEQ / 256), 512, 0, stream>>>(
            AO, wb, out, DIM, 0);
    } else if (ws_size >= needU) {
        bf16* xb = AO + SZ;
        bf16* wb = xb + SZ;        // [DIM][DIM] bf16, reused per weight

        dim3 gU(DIM / 256, SEQ / 256);   // (16,8) = 128 blocks

        convert_bf16<<<(int)(SZ / 4 / 256), 256, 0, stream>>>(x, xb);

        convt_bf16<<<tGw, 256, 0, stream>>>(wq, wb, DIM, DIM);
        gemm_pipe<4, bf16><<<gU, 512, 0, stream>>>(xb, wb, Q, DIM, 0);
        convt_bf16<<<tGw, 256, 0, stream>>>(wk, wb, DIM, DIM);
        gemm_pipe<4, bf16><<<gU, 512, 0, stream>>>(xb, wb, Kb, DIM, 0);
        convt_bf16<<<tGw, 256, 0, stream>>>(wv, wb, DIM, DIM);
        gemm_pipe<4, bf16><<<gU, 512, 0, stream>>>(xb, wb, V, DIM, 0);

        rope_kernel<<<(SEQ * (DIM / 2)) / 256, 256, 0, stream>>>(Q, Kb, fc, fs);
        attn_kernel<<<dim3(SEQ / 128, NH), 256, 0, stream>>>(Q, Kb, V, AO);

        convt_bf16<<<tGw, 256, 0, stream>>>(wo, wb, DIM, DIM);
        gemm_pipe<2, float><<<dim3(DIM / 128, SEQ / 256), 512, 0, stream>>>(
            AO, wb, out, DIM, 0);
    } else {
        dim3 gGn(DIM / 128, SEQ / 128);
        gemm_nat<float, bf16><<<gGn, 256, 0, stream>>>(x, wq, Q,  SEQ, DIM, DIM);
        gemm_nat<float, bf16><<<gGn, 256, 0, stream>>>(x, wk, Kb, SEQ, DIM, DIM);
        gemm_nat<float, bf16><<<gGn, 256, 0, stream>>>(x, wv, V,  SEQ, DIM, DIM);
        rope_kernel<<<(SEQ * (DIM / 2)) / 256, 256, 0, stream>>>(Q, Kb, fc, fs);
        attn_kernel<<<dim3(SEQ / 128, NH), 256, 0, stream>>>(Q, Kb, V, AO);
        gemm_nat<bf16, float><<<gGn, 256, 0, stream>>>(AO, wo, out, SEQ, DIM, DIM);
    }
}